// Round 7
// baseline (127.802 us; speedup 1.0000x reference)
//
#include <hip/hip_runtime.h>
#include <math.h>

#define SLEN 2048
#define DMODEL 1024
#define NHEADS 16
#define DK 64
#define NBATCH 2
#define M_TOT (NBATCH * SLEN)   // 4096
#define NQKV (3 * DMODEL)       // 3072

typedef __bf16 bf16x8 __attribute__((ext_vector_type(8)));
typedef float f32x4 __attribute__((ext_vector_type(4)));
typedef float f32x16 __attribute__((ext_vector_type(16)));

// f32 -> bf16 round-to-nearest-even
static __device__ __forceinline__ unsigned short f2bf(float f) {
    unsigned int u = __float_as_uint(f);
    u += 0x7fffu + ((u >> 16) & 1u);
    return (unsigned short)(u >> 16);
}

// pack two f32 -> bf16x2 dword (lo = a, hi = b)
static __device__ __forceinline__ unsigned cvtpk(float a, float b) {
    unsigned r;
    asm("v_cvt_pk_bf16_f32 %0, %1, %2" : "=v"(r) : "v"(a), "v"(b));
    return r;
}

#if __has_builtin(__builtin_amdgcn_exp2f)
#define EXP2(x) __builtin_amdgcn_exp2f(x)
#else
#define EXP2(x) exp2f(x)
#endif

// async global->LDS, 16 B per lane. lds dest is wave-uniform base + lane*16.
static __device__ __forceinline__ void gload16(const void* g, void* l) {
    __builtin_amdgcn_global_load_lds(
        (const __attribute__((address_space(1))) unsigned int*)g,
        (__attribute__((address_space(3))) unsigned int*)l, 16, 0, 0);
}

// ---------------------------------------------------------------------------
// x f32 -> bf16 (flat copy)
// ---------------------------------------------------------------------------
__global__ __launch_bounds__(256)
void convert_bf16(const float* __restrict__ X, unsigned short* __restrict__ Xb, int n4)
{
    int i = blockIdx.x * 256 + threadIdx.x;
    if (i < n4) {
        float4 v = *(const float4*)&X[(size_t)i * 4];
        ushort4 o;
        o.x = f2bf(v.x); o.y = f2bf(v.y); o.z = f2bf(v.z); o.w = f2bf(v.w);
        *(ushort4*)&Xb[(size_t)i * 4] = o;
    }
}

// ---------------------------------------------------------------------------
// W [1024][1024] f32 -> Wt [N][K] bf16 (transposed, so K is contiguous)
// ---------------------------------------------------------------------------
__global__ __launch_bounds__(256)
void transpose_w(const float* __restrict__ W, unsigned short* __restrict__ Wt)
{
    __shared__ float t[64][65];
    const int tid = threadIdx.x;
    const int c0 = blockIdx.x * 64, r0 = blockIdx.y * 64;
    const int tr = tid >> 4, tc = (tid & 15) * 4;
    #pragma unroll
    for (int rr = 0; rr < 4; ++rr) {
        int row = rr * 16 + tr;
        float4 v = *(const float4*)&W[(size_t)(r0 + row) * DMODEL + c0 + tc];
        t[row][tc + 0] = v.x; t[row][tc + 1] = v.y;
        t[row][tc + 2] = v.z; t[row][tc + 3] = v.w;
    }
    __syncthreads();
    #pragma unroll
    for (int rr = 0; rr < 4; ++rr) {
        int orow = rr * 16 + tr;
        ushort4 o;
        o.x = f2bf(t[tc + 0][orow]);
        o.y = f2bf(t[tc + 1][orow]);
        o.z = f2bf(t[tc + 2][orow]);
        o.w = f2bf(t[tc + 3][orow]);
        *(ushort4*)&Wt[(size_t)(c0 + orow) * DMODEL + r0 + tc] = o;
    }
}

// ---------------------------------------------------------------------------
// bf16 MFMA GEMM: C[M,N] = A[M,K] @ Bt[N,K]^T.  BM=BN=128, BK=64, 4 waves.
// Double-buffered LDS 2-phase rotation.
// MODE 0: C f32 [M][N]          (att @ Wo -> d_out)
// MODE 1: N=3072 QKV fused; Q,K: RoPE; Q scaled by 0.125*log2e -> [bh][s][64];
//         V -> [bh][64][s] (transposed)
// ---------------------------------------------------------------------------
template<int MODE>
__global__ __launch_bounds__(256)
void gemm_mfma(const unsigned short* __restrict__ A,
               const unsigned short* __restrict__ Bt,
               float* __restrict__ C,
               unsigned short* __restrict__ Qd,
               unsigned short* __restrict__ Kd,
               unsigned short* __restrict__ Vtd,
               const int* __restrict__ pos,
               int N, int K)
{
    __shared__ unsigned short AB[2 * 2 * 128 * 64];   // [buf][A/B][128][64], 64 KB
    const int tid = threadIdx.x;
    const int w = tid >> 6, l = tid & 63;
    const int m0 = blockIdx.y * 128, n0 = blockIdx.x * 128;
    const int wr = (w >> 1) * 64, wc = (w & 1) * 64;
    const int lr = l >> 3, lp = l & 7;

    f32x4 acc[4][4] = {};

    auto STAGE = [&](int k0, int buf) {
        unsigned short* Asd = AB + buf * (2 * 128 * 64);
        unsigned short* Bsd = Asd + 128 * 64;
        #pragma unroll
        for (int i = 0; i < 4; ++i) {
            int row = w * 32 + i * 8 + lr;
            int s = lp ^ (row & 7);
            gload16(A  + (size_t)(m0 + row) * K + k0 + s * 8, (void*)(Asd + (w * 32 + i * 8) * 64));
            gload16(Bt + (size_t)(n0 + row) * K + k0 + s * 8, (void*)(Bsd + (w * 32 + i * 8) * 64));
        }
    };

    const int nt = K >> 6;
    STAGE(0, 0);

    for (int t = 0; t < nt; ++t) {
        __syncthreads();                       // stage(t) landed; buf[(t+1)&1] free
        if (t + 1 < nt) STAGE((t + 1) << 6, (t + 1) & 1);
        const char* Asb = (const char*)AB + (t & 1) * 32768;
        const char* Bsb = Asb + 16384;
        #pragma unroll
        for (int ks = 0; ks < 2; ++ks) {
            bf16x8 af[4], bfr[4];
            #pragma unroll
            for (int i = 0; i < 4; ++i) {
                int row = wr + i * 16 + (l & 15);
                int slot = (ks * 4 + (l >> 4)) ^ (row & 7);
                af[i] = *(const bf16x8*)(Asb + row * 128 + slot * 16);
            }
            #pragma unroll
            for (int j = 0; j < 4; ++j) {
                int row = wc + j * 16 + (l & 15);
                int slot = (ks * 4 + (l >> 4)) ^ (row & 7);
                bfr[j] = *(const bf16x8*)(Bsb + row * 128 + slot * 16);
            }
            __builtin_amdgcn_s_setprio(1);
            #pragma unroll
            for (int i = 0; i < 4; ++i)
                #pragma unroll
                for (int j = 0; j < 4; ++j)
                    acc[i][j] = __builtin_amdgcn_mfma_f32_16x16x32_bf16(af[i], bfr[j], acc[i][j], 0, 0, 0);
            __builtin_amdgcn_s_setprio(0);
        }
    }

    // Epilogue. C/D layout: col = lane&15, row = (lane>>4)*4 + reg.
    if (MODE == 0) {
        #pragma unroll
        for (int i = 0; i < 4; ++i)
            #pragma unroll
            for (int j = 0; j < 4; ++j)
                #pragma unroll
                for (int r = 0; r < 4; ++r) {
                    int row = m0 + wr + i * 16 + (l >> 4) * 4 + r;
                    int col = n0 + wc + j * 16 + (l & 15);
                    C[(size_t)row * N + col] = acc[i][j][r];
                }
    } else {
        const int seg = (n0 + wc) >> 10;  // 0=Q 1=K 2=V (block-uniform)
        #pragma unroll
        for (int i = 0; i < 4; ++i) {
            const int mbase = m0 + wr + i * 16 + (l >> 4) * 4;
            #pragma unroll
            for (int j = 0; j < 4; ++j) {
                const int n = n0 + wc + j * 16 + (l & 15);
                const int h = (n >> 6) & 15;
                const int d = n & 63;
                if (seg < 2) {
                    unsigned short* dst = (seg == 0) ? Qd : Kd;
                    const int de = d & ~1;
                    const float freq = __expf((float)de * (-9.210340371976184f / 64.f));
                    #pragma unroll
                    for (int r = 0; r < 4; ++r) {
                        const int m = mbase + r;
                        const int b = m >> 11, s = m & 2047;
                        float v = acc[i][j][r];
                        float p2 = __shfl_xor(v, 1);   // partner column of the RoPE pair
                        float ang = (float)pos[m] * freq;
                        float sn, cs;
                        __sincosf(ang, &sn, &cs);
                        float res = ((l & 1) == 0) ? (v * cs - p2 * sn) : (p2 * sn + v * cs);
                        if (seg == 0) res *= 0.18033688011112042f;  // 0.125*log2(e)
                        dst[((size_t)(b * NHEADS + h) * SLEN + s) * DK + d] = f2bf(res);
                    }
                } else {
                    const int b = mbase >> 11, s0 = mbase & 2047;
                    ushort4 o;
                    o.x = f2bf(acc[i][j][0]); o.y = f2bf(acc[i][j][1]);
                    o.z = f2bf(acc[i][j][2]); o.w = f2bf(acc[i][j][3]);
                    *(ushort4*)&Vtd[((size_t)(b * NHEADS + h) * DK + d) * SLEN + s0] = o;
                }
            }
        }
    }
}

// ---------------------------------------------------------------------------
// MFMA flash attention v5: 32x32x16 MFMA, 2-wave blocks for occupancy.
// Block = 64 q of one (b,h); wave w owns q-cols w*32..+31 over ALL kv tiles.
// KV tile 64, LDS dbuf 2x16KB. Grid 1024, LPT order (qt descending) within
// XCD stripes (4 bh per XCD -> K/V L2-resident).
// S^T = K·Q: lane (h=l>>5, c31=l&31) owns col q, kv rows mt*32+(r&3)+8(r>>2)+4h.
// P^T -> PV B-frag: 4 cvt_pk + 4 shfl_xor(32) + selects per 16-k chunk
// (verified R6). Per-lane partial lsum; single cross-h exchange at the end.
// ---------------------------------------------------------------------------
__global__ __launch_bounds__(128)
void attn_mfma(const unsigned short* __restrict__ Q,
               const unsigned short* __restrict__ K,
               const unsigned short* __restrict__ Vt,
               unsigned short* __restrict__ Oa)
{
    __shared__ char smem[32768];   // [buf 16KB][ K 8KB | V^T 8KB ]
    const int tid = threadIdx.x;
    const int w = tid >> 6, l = tid & 63;
    const int h = l >> 5, c31 = l & 31;

    // LPT within XCD stripe: xcd = id&7, j = id>>3; qt descending (heavy first),
    // bh clustered 4 per XCD.
    const int id = blockIdx.x;
    const int j = id >> 3;
    const int qt = 31 - (j >> 2);           // 64-row q tile, 0..31
    const int bh = (id & 7) * 4 + (j & 3);
    const int nkt = qt + 1;

    const unsigned short* Qb = Q + (size_t)bh * SLEN * DK;
    const unsigned short* Kb = K + (size_t)bh * SLEN * DK;
    const unsigned short* Vb = Vt + (size_t)bh * DK * SLEN;

    const int q_g = qt * 64 + w * 32 + c31;

    // Q B-frags (B col = q, k = kb*16 + h*8): 4 x 16B global loads
    bf16x8 qf[4];
    #pragma unroll
    for (int kb = 0; kb < 4; ++kb)
        qf[kb] = *(const bf16x8*)(Qb + (size_t)q_g * DK + kb * 16 + h * 8);

    float m = -1e30f, lsum = 0.f;
    f32x16 oacc[2] = {};

    // staging: 128 threads, 4 issues each for K and V; issue i covers
    // rows i*16 + w*8 + (l>>3), slot l&7 (dest linear: wave base + lane*16)
    const int srow_i = w * 8 + (l >> 3);
    const int sslot = l & 7;

    auto STAGE = [&](int kt, int buf) {
        char* base = smem + buf * 16384;
        #pragma unroll
        for (int i = 0; i < 4; ++i) {
            int kv = i * 16 + srow_i;
            gload16(Kb + (size_t)(kt * 64 + kv) * DK + (sslot ^ (kv & 7)) * 8,
                    (void*)(base + i * 2048 + w * 1024));
        }
        #pragma unroll
        for (int i = 0; i < 4; ++i) {
            int d = i * 16 + srow_i;
            gload16(Vb + (size_t)d * SLEN + kt * 64 + (sslot ^ (d & 7)) * 8,
                    (void*)(base + 8192 + i * 2048 + w * 1024));
        }
    };

    STAGE(0, 0);

    for (int kt = 0; kt < nkt; ++kt) {
        __syncthreads();                        // stage(kt) landed; other buf free
        if (kt + 1 < nkt) STAGE(kt + 1, (kt + 1) & 1);

        const char* Kbuf = smem + (kt & 1) * 16384;
        const char* Vbuf = Kbuf + 8192;

        // S^T = K · Q
        f32x16 sacc[2] = {};
        __builtin_amdgcn_s_setprio(1);
        #pragma unroll
        for (int kb = 0; kb < 4; ++kb)
            #pragma unroll
            for (int mt = 0; mt < 2; ++mt) {
                int row = mt * 32 + c31;
                int slot = (kb * 2 + h) ^ (row & 7);
                bf16x8 kf = *(const bf16x8*)(Kbuf + row * 128 + slot * 16);
                sacc[mt] = __builtin_amdgcn_mfma_f32_32x32x16_bf16(kf, qf[kb], sacc[mt], 0, 0, 0);
            }
        __builtin_amdgcn_s_setprio(0);

        // causal mask (diagonal tile only): kv_off > w*32 + c31 masked
        if (kt == qt) {
            #pragma unroll
            for (int mt = 0; mt < 2; ++mt)
                #pragma unroll
                for (int r = 0; r < 16; ++r) {
                    int kvo = mt * 32 + (r & 3) + 8 * (r >> 2) + 4 * h;
                    if (kvo > w * 32 + c31) sacc[mt][r] = -1e30f;
                }
        }

        // column max: local tree + lane^32 exchange
        float t16[16];
        #pragma unroll
        for (int r = 0; r < 16; ++r) t16[r] = fmaxf(sacc[0][r], sacc[1][r]);
        #pragma unroll
        for (int s = 8; s > 0; s >>= 1)
            #pragma unroll
            for (int r = 0; r < s; ++r) t16[r] = fmaxf(t16[r], t16[r + s]);
        float mx = t16[0];
        mx = fmaxf(mx, __shfl_xor(mx, 32));

        if (mx > m + 6.0f) {        // defer-max
            float corr = EXP2(m - mx);
            m = mx;
            lsum *= corr;
            oacc[0] *= corr;
            oacc[1] *= corr;
        }

        // P = exp2(S - m) in place; per-lane partial sum (cross-h merge at end)
        float ps = 0.f;
        #pragma unroll
        for (int mt = 0; mt < 2; ++mt)
            #pragma unroll
            for (int r = 0; r < 16; ++r) {
                float e = EXP2(sacc[mt][r] - m);
                sacc[mt][r] = e;
                ps += e;
            }
        lsum += ps;

        // O^T += V^T · P^T ; B-frag per 16-k chunk (verified R6):
        //   d0=[pk0_L|pk2_L] d1=[pk1_L|pk3_L] d2=[pk0_H|pk2_H] d3=[pk1_H|pk3_H]
        #pragma unroll
        for (int ks = 0; ks < 4; ++ks) {
            const int mt = ks >> 1, rb = (ks & 1) * 8;
            unsigned pk0 = cvtpk(sacc[mt][rb + 0], sacc[mt][rb + 1]);
            unsigned pk1 = cvtpk(sacc[mt][rb + 2], sacc[mt][rb + 3]);
            unsigned pk2 = cvtpk(sacc[mt][rb + 4], sacc[mt][rb + 5]);
            unsigned pk3 = cvtpk(sacc[mt][rb + 6], sacc[mt][rb + 7]);
            unsigned s0 = (unsigned)__shfl_xor((int)pk0, 32);
            unsigned s1 = (unsigned)__shfl_xor((int)pk1, 32);
            unsigned s2 = (unsigned)__shfl_xor((int)pk2, 32);
            unsigned s3 = (unsigned)__shfl_xor((int)pk3, 32);
            union { unsigned u[4]; bf16x8 v; } pf;
            pf.u[0] = (h == 0) ? pk0 : s2;
            pf.u[1] = (h == 0) ? pk1 : s3;
            pf.u[2] = (h == 0) ? s0 : pk2;
            pf.u[3] = (h == 0) ? s1 : pk3;
            __builtin_amdgcn_s_setprio(1);
            #pragma unroll
            for (int mt2 = 0; mt2 < 2; ++mt2) {
                int row = mt2 * 32 + c31;
                int slot = (ks * 2 + h) ^ (row & 7);
                bf16x8 vf = *(const bf16x8*)(Vbuf + row * 128 + slot * 16);
                oacc[mt2] = __builtin_amdgcn_mfma_f32_32x32x16_bf16(vf, pf.v, oacc[mt2], 0, 0, 0);
            }
            __builtin_amdgcn_s_setprio(0);
        }
    }

    // cross-h column sum merge (single exchange)
    lsum += __shfl_xor(lsum, 32);

    __syncthreads();   // both waves done with K/V buffers

    // epilogue: O^T[d][q] -> Os[64 q][64 d] bf16 (8KB, swizzled), then store
    unsigned short* Os = (unsigned short*)smem;
    const float inv = 1.f / lsum;
    const int ql = w * 32 + c31;
    #pragma unroll
    for (int mt = 0; mt < 2; ++mt)
        #pragma unroll
        for (int rq = 0; rq < 4; ++rq) {
            uint2 pv;
            pv.x = cvtpk(oacc[mt][rq * 4 + 0] * inv, oacc[mt][rq * 4 + 1] * inv);
            pv.y = cvtpk(oacc[mt][rq * 4 + 2] * inv, oacc[mt][rq * 4 + 3] * inv);
            int dbyte = mt * 64 + rq * 16 + h * 8;
            *(uint2*)((char*)Os + ql * 128 + (dbyte ^ ((ql & 7) << 4))) = pv;
        }
    __syncthreads();

    const int b = bh >> 4, hh = bh & 15;
    const int jj = tid & 7;
    #pragma unroll
    for (int p = 0; p < 4; ++p) {
        int qp = p * 16 + (tid >> 3);
        uint4 vv = *(const uint4*)((const char*)Os + qp * 128 + ((jj ^ (qp & 7)) << 4));
        int srow = qt * 64 + qp;
        *(uint4*)&Oa[((size_t)(b * SLEN + srow)) * DMODEL + hh * DK + jj * 8] = vv;
    }
}

extern "C" void kernel_launch(void* const* d_in, const int* in_sizes, int n_in,
                              void* d_out, int out_size, void* d_ws, size_t ws_size,
                              hipStream_t stream)
{
    const float* x  = (const float*)d_in[0];
    const float* Wq = (const float*)d_in[1];
    const float* Wk = (const float*)d_in[2];
    const float* Wv = (const float*)d_in[3];
    const float* Wo = (const float*)d_in[4];
    const int*  pos = (const int*)d_in[5];
    float* out = (float*)d_out;

    char* ws = (char*)d_ws;
    const size_t MB = 1024 * 1024;
    unsigned short* xb   = (unsigned short*)(ws);             // 8 MB
    unsigned short* Wcat = (unsigned short*)(ws + 8 * MB);    // 6 MB
    unsigned short* Wot  = (unsigned short*)(ws + 14 * MB);   // 2 MB
    unsigned short* Qws  = (unsigned short*)(ws + 16 * MB);   // 8 MB [32][2048][64]
    unsigned short* Kws  = (unsigned short*)(ws + 24 * MB);   // 8 MB [32][2048][64]
    unsigned short* Vtws = (unsigned short*)(ws + 32 * MB);   // 8 MB [32][64][2048]
    unsigned short* attb = (unsigned short*)(ws + 40 * MB);   // 8 MB [4096][1024]

    convert_bf16<<<4096, 256, 0, stream>>>(x, xb, M_TOT * DMODEL / 4);
    transpose_w<<<dim3(16, 16), 256, 0, stream>>>(Wq, Wcat);
    transpose_w<<<dim3(16, 16), 256, 0, stream>>>(Wk, Wcat + 1024 * 1024);
    transpose_w<<<dim3(16, 16), 256, 0, stream>>>(Wv, Wcat + 2 * 1024 * 1024);
    transpose_w<<<dim3(16, 16), 256, 0, stream>>>(Wo, Wot);

    gemm_mfma<1><<<dim3(NQKV / 128, M_TOT / 128), 256, 0, stream>>>(
        xb, Wcat, nullptr, Qws, Kws, Vtws, pos, NQKV, DMODEL);

    attn_mfma<<<1024, 128, 0, stream>>>(Qws, Kws, Vtws, attb);

    gemm_mfma<0><<<dim3(DMODEL / 128, M_TOT / 128), 256, 0, stream>>>(
        attb, Wot, out, nullptr, nullptr, nullptr, nullptr, DMODEL, DMODEL);
}